// Round 1
// baseline (680.509 us; speedup 1.0000x reference)
//
#include <hip/hip_runtime.h>
#include <hip/hip_bf16.h>
#include <stdint.h>

#define B_ 8
#define L_ 2048
#define V_ 8192
#define C_ 64
#define F_ 130   // 2*(C+1)

typedef float    f32x4  __attribute__((ext_vector_type(4)));
typedef short    s16x8  __attribute__((ext_vector_type(8)));
typedef __bf16   bf16x8 __attribute__((ext_vector_type(8)));
typedef uint32_t u32x4  __attribute__((ext_vector_type(4)));

__device__ __forceinline__ uint32_t pack2bf(float a, float b) {
  uint16_t ua = __builtin_bit_cast(uint16_t, (__bf16)a);
  uint16_t ub = __builtin_bit_cast(uint16_t, (__bf16)b);
  return (uint32_t)ua | ((uint32_t)ub << 16);
}

__device__ __forceinline__ float wave_sum(float v) {
  v += __shfl_xor(v, 1);  v += __shfl_xor(v, 2);  v += __shfl_xor(v, 4);
  v += __shfl_xor(v, 8);  v += __shfl_xor(v, 16); v += __shfl_xor(v, 32);
  return v;
}

// ---------------------------------------------------------------------------
// PRE: blocks [0,512): feats -> bf16 transposed fT[p][ch][V]
//      blocks [512,1024): verts -> SoA vS[p][{x,y,z,n2}][V]
// p = side*8 + b
// ---------------------------------------------------------------------------
__global__ __launch_bounds__(256) void pre_kernel(
    const float* __restrict__ verts_l, const float* __restrict__ verts_r,
    const float* __restrict__ feats_l, const float* __restrict__ feats_r,
    uint16_t* __restrict__ fT, float* __restrict__ vS)
{
  const int blk = blockIdx.x;
  const int tid = threadIdx.x;
  if (blk < 512) {
    const int p = blk >> 5, chunk = blk & 31;
    const int side = p >> 3, bb = p & 7;
    const float* src = (side ? feats_r : feats_l) + (size_t)bb * (V_ * C_);
    const int wv = tid >> 6, lane = tid & 63;       // lane = channel
    const int k0 = chunk * 256 + wv * 64;
    uint16_t* dst = fT + (size_t)(p * 64 + lane) * V_ + k0;
    #pragma unroll
    for (int j = 0; j < 8; ++j) {
      float f[8];
      #pragma unroll
      for (int e = 0; e < 8; ++e)
        f[e] = src[(size_t)(k0 + j * 8 + e) * C_ + lane];   // coalesced across lanes
      u32x4 val = { pack2bf(f[0], f[1]), pack2bf(f[2], f[3]),
                    pack2bf(f[4], f[5]), pack2bf(f[6], f[7]) };
      *(u32x4*)(dst + j * 8) = val;
    }
  } else {
    const int blk2 = blk - 512;
    const int p = blk2 >> 5, chunk = blk2 & 31;
    const int side = p >> 3, bb = p & 7;
    const float* src = (side ? verts_r : verts_l) + (size_t)bb * (V_ * 3);
    const int v = chunk * 256 + tid;
    const float x = src[v * 3 + 0], y = src[v * 3 + 1], z = src[v * 3 + 2];
    const float n2 = x * x + y * y + z * z;
    float* d = vS + (size_t)p * (4 * V_);
    d[0 * V_ + v] = x; d[1 * V_ + v] = y; d[2 * V_ + v] = z; d[3 * V_ + v] = n2;
  }
}

// ---------------------------------------------------------------------------
// INTERP: one block = 64 L-rows x 64 channels for one (side,b) pair.
// 4 waves; wave owns 16 rows (A rows = lane&15), all 64 cols (4 col-tiles).
// K-loop over V in 64-chunks, reg-staged double-buffered LDS, 1 barrier/iter.
// W generated in fp32, packed bf16 -> mfma_f32_16x16x32_bf16.
// feats LDS tile XOR-swizzled: byte = ch*128 + ((k*2) ^ ((ch&7)<<4)).
// ---------------------------------------------------------------------------
__global__ __launch_bounds__(256, 2) void interp_kernel(
    const float* __restrict__ locs_l, const float* __restrict__ locs_r,
    const uint16_t* __restrict__ fT, const float* __restrict__ vS,
    float* __restrict__ xbuf)
{
  __shared__ __align__(16) char  flds[2][8192];
  __shared__ __align__(16) float vlds[2][4][64];

  const int bid = blockIdx.x;
  // XCD-aware swizzle: pair p pinned to XCD p/2 (grid 512 = 8 XCD * 64)
  const int p  = (bid & 7) * 2 + ((bid >> 3) >> 5);
  const int lt = (bid >> 3) & 31;
  const int side = p >> 3, bb = p & 7;
  const int tid = threadIdx.x;
  const int wid = tid >> 6, lane = tid & 63;
  const int ln15 = lane & 15, lg = lane >> 4;

  const float* locs = (side ? locs_r : locs_l) + (size_t)bb * (L_ * 3);
  const int lbase = lt * 64;
  const int arow = lbase + wid * 16 + ln15;
  const float px = locs[arow * 3 + 0];
  const float py = locs[arow * 3 + 1];
  const float pz = locs[arow * 3 + 2];
  const float pn2 = px * px + py * py + pz * pz;

  const uint16_t* fbase = fT + (size_t)p * (C_ * V_);
  const float*    vbase = vS + (size_t)p * (4 * V_);

  // staging roles: feats: thread t -> ch=t/4, 16 k's; verts: comp=t/64, k=t%64
  const int sch = tid >> 2, skq = tid & 3;
  const uint16_t* sgf = fbase + (size_t)sch * V_ + skq * 16;
  const int swb = sch * 128 + ((skq * 32) ^ ((sch & 7) << 4));
  const int svc = tid >> 6, svk = tid & 63;
  const float* sgv = vbase + (size_t)svc * V_ + svk;

  const int xorv = (ln15 & 7) << 4;
  constexpr float KEXP = -0.57707801635558535f;  // -1/(2.5*ln2)

  f32x4 acc0 = {0.f,0.f,0.f,0.f}, acc1 = {0.f,0.f,0.f,0.f};
  f32x4 acc2 = {0.f,0.f,0.f,0.f}, acc3 = {0.f,0.f,0.f,0.f};
  float dens = 0.f;

  { // prologue: stage tile 0
    u32x4 f0 = *(const u32x4*)(sgf);
    u32x4 f1 = *(const u32x4*)(sgf + 8);
    float v0 = sgv[0];
    *(u32x4*)&flds[0][swb]      = f0;
    *(u32x4*)&flds[0][swb ^ 16] = f1;
    vlds[0][svc][svk] = v0;
  }
  __syncthreads();

  for (int kt = 0; kt < 128; ++kt) {
    const int cur = kt & 1;
    u32x4 nf0, nf1; float nv;
    const bool more = (kt + 1) < 128;
    if (more) {  // issue prefetch loads early; latency hides under compute
      const uint16_t* g = sgf + (size_t)(kt + 1) * 64;
      nf0 = *(const u32x4*)(g);
      nf1 = *(const u32x4*)(g + 8);
      nv  = sgv[(kt + 1) * 64];
    }
    const char* fl = flds[cur];
    #pragma unroll
    for (int kk = 0; kk < 2; ++kk) {
      const int kof = kk * 32 + lg * 8;
      // broadcast reads (16 lanes/group share addr) -> conflict-free
      f32x4 vx0 = *(const f32x4*)&vlds[cur][0][kof];
      f32x4 vx1 = *(const f32x4*)&vlds[cur][0][kof + 4];
      f32x4 vy0 = *(const f32x4*)&vlds[cur][1][kof];
      f32x4 vy1 = *(const f32x4*)&vlds[cur][1][kof + 4];
      f32x4 vz0 = *(const f32x4*)&vlds[cur][2][kof];
      f32x4 vz1 = *(const f32x4*)&vlds[cur][2][kof + 4];
      f32x4 vn0 = *(const f32x4*)&vlds[cur][3][kof];
      f32x4 vn1 = *(const f32x4*)&vlds[cur][3][kof + 4];
      bf16x8 av;
      #pragma unroll
      for (int e = 0; e < 8; ++e) {
        const float vx = (e < 4) ? vx0[e] : vx1[e - 4];
        const float vy = (e < 4) ? vy0[e] : vy1[e - 4];
        const float vz = (e < 4) ? vz0[e] : vz1[e - 4];
        const float vn = (e < 4) ? vn0[e] : vn1[e - 4];
        const float t  = fmaf(px, vx, fmaf(py, vy, pz * vz));
        const float d2 = fmaf(-2.f, t, pn2 + vn);
        const float d  = __builtin_amdgcn_sqrtf(fmaxf(d2, 0.f));
        const float w  = exp2f(d * KEXP);
        dens += w;                       // fp32 dens (pre-normalization sum)
        av[e] = (__bf16)w;
      }
      const s16x8 afrag = __builtin_bit_cast(s16x8, av);
      const int ab = ln15 * 128 + (((kk << 6) | (lg << 4)) ^ xorv);
      const s16x8 b0 = *(const s16x8*)(fl + ab);
      const s16x8 b1 = *(const s16x8*)(fl + ab + 2048);
      const s16x8 b2 = *(const s16x8*)(fl + ab + 4096);
      const s16x8 b3 = *(const s16x8*)(fl + ab + 6144);
      acc0 = __builtin_amdgcn_mfma_f32_16x16x32_bf16(afrag, b0, acc0, 0, 0, 0);
      acc1 = __builtin_amdgcn_mfma_f32_16x16x32_bf16(afrag, b1, acc1, 0, 0, 0);
      acc2 = __builtin_amdgcn_mfma_f32_16x16x32_bf16(afrag, b2, acc2, 0, 0, 0);
      acc3 = __builtin_amdgcn_mfma_f32_16x16x32_bf16(afrag, b3, acc3, 0, 0, 0);
    }
    if (more) {  // write next buffer (disjoint from buffer being read)
      const int nb = cur ^ 1;
      *(u32x4*)&flds[nb][swb]      = nf0;
      *(u32x4*)&flds[nb][swb ^ 16] = nf1;
      vlds[nb][svc][svk] = nv;
    }
    __syncthreads();
  }

  // dens: combine the 4 k-groups -> every lane holds full dens of row lane&15
  dens += __shfl_xor(dens, 16);
  dens += __shfl_xor(dens, 32);

  // D layout: col = lane&15, row = (lane>>4)*4 + reg
  #pragma unroll
  for (int r = 0; r < 4; ++r) {
    const int drow = lg * 4 + r;
    const float dr  = __shfl(dens, drow);   // lane 'drow' holds that row's dens
    const float inv = 1.0f / dr;
    const size_t base = ((size_t)bb * L_ + (lbase + wid * 16 + drow)) * F_ + side * 65;
    xbuf[base      + ln15] = acc0[r] * inv;
    xbuf[base + 16 + ln15] = acc1[r] * inv;
    xbuf[base + 32 + ln15] = acc2[r] * inv;
    xbuf[base + 48 + ln15] = acc3[r] * inv;
  }
  if (lane < 16) {
    const size_t base = ((size_t)bb * L_ + (lbase + wid * 16 + lane)) * F_ + side * 65;
    xbuf[base + 64] = dens;
  }
}

// ---------------------------------------------------------------------------
// MLP: out = w2 . relu(x @ w1^T + b1) + b2, fp32.
// Block: 256 thr, 16 rows; w1 in LDS pitch 133 (conflict-free), x pitch 132.
// Lane j handles cols {j, j+64}; cols 128/129 via wave reduction.
// ---------------------------------------------------------------------------
__global__ __launch_bounds__(256, 2) void mlp_kernel(
    const float* __restrict__ xbuf, const float* __restrict__ w1,
    const float* __restrict__ b1, const float* __restrict__ w2,
    const float* __restrict__ b2, float* __restrict__ outp)
{
  __shared__ float w1s[130 * 133];
  __shared__ __align__(16) float xs[16][132];
  const int tid = threadIdx.x;
  const int rbase = blockIdx.x * 16;

  for (int idx = tid; idx < 130 * 130; idx += 256) {
    const int j = idx / 130;
    const int i = idx - j * 130;
    w1s[j * 133 + i] = w1[idx];
  }
  for (int idx = tid; idx < 16 * 130; idx += 256) {
    const int r = idx / 130;
    const int i = idx - r * 130;
    xs[r][i] = xbuf[(size_t)(rbase + r) * F_ + i];
  }
  __syncthreads();

  const int wv = tid >> 6, lane = tid & 63;
  const int r0 = wv * 4;                      // wave -> 4 rows
  float h0[4] = {0.f,0.f,0.f,0.f}, h1[4] = {0.f,0.f,0.f,0.f};
  const float* wr0 = w1s + lane * 133;
  const float* wr1 = w1s + (lane + 64) * 133;

  for (int i = 0; i < 128; i += 4) {
    const float a0 = wr0[i], a1 = wr0[i+1], a2 = wr0[i+2], a3 = wr0[i+3];
    const float c0 = wr1[i], c1 = wr1[i+1], c2 = wr1[i+2], c3 = wr1[i+3];
    #pragma unroll
    for (int r = 0; r < 4; ++r) {
      const f32x4 xv = *(const f32x4*)&xs[r0 + r][i];
      h0[r] = fmaf(xv.x, a0, h0[r]); h0[r] = fmaf(xv.y, a1, h0[r]);
      h0[r] = fmaf(xv.z, a2, h0[r]); h0[r] = fmaf(xv.w, a3, h0[r]);
      h1[r] = fmaf(xv.x, c0, h1[r]); h1[r] = fmaf(xv.y, c1, h1[r]);
      h1[r] = fmaf(xv.z, c2, h1[r]); h1[r] = fmaf(xv.w, c3, h1[r]);
    }
  }
  { // i-tail: 128,129
    const float a0 = wr0[128], a1 = wr0[129], c0 = wr1[128], c1 = wr1[129];
    #pragma unroll
    for (int r = 0; r < 4; ++r) {
      const float x0 = xs[r0 + r][128], x1 = xs[r0 + r][129];
      h0[r] = fmaf(x0, a0, fmaf(x1, a1, h0[r]));
      h1[r] = fmaf(x0, c0, fmaf(x1, c1, h1[r]));
    }
  }
  // j-tail: columns 128,129 via per-row wave reduce over i
  const float* wr2 = w1s + 128 * 133;
  const float* wr3 = w1s + 129 * 133;
  float hp2[4], hp3[4];
  #pragma unroll
  for (int r = 0; r < 4; ++r) {
    const float xa = xs[r0 + r][lane];
    const float xb = xs[r0 + r][lane + 64];
    float p2 = wr2[lane] * xa + wr2[lane + 64] * xb;
    float p3 = wr3[lane] * xa + wr3[lane + 64] * xb;
    if (lane < 2) {
      const float xc = xs[r0 + r][128 + lane];
      p2 += wr2[128 + lane] * xc;
      p3 += wr3[128 + lane] * xc;
    }
    hp2[r] = wave_sum(p2);
    hp3[r] = wave_sum(p3);
  }
  const float b1a = b1[lane], b1b = b1[lane + 64];
  const float w2a = w2[lane], w2b = w2[lane + 64];
  const float b1c = b1[128], b1d = b1[129];
  const float w2c = w2[128], w2d = w2[129];
  const float b2v = b2[0];
  #pragma unroll
  for (int r = 0; r < 4; ++r) {
    float o = w2a * fmaxf(h0[r] + b1a, 0.f) + w2b * fmaxf(h1[r] + b1b, 0.f);
    o = wave_sum(o);
    if (lane == 0) {
      o += w2c * fmaxf(hp2[r] + b1c, 0.f) + w2d * fmaxf(hp3[r] + b1d, 0.f);
      outp[rbase + r0 + r] = o + b2v;
    }
  }
}

// ---------------------------------------------------------------------------
extern "C" void kernel_launch(void* const* d_in, const int* in_sizes, int n_in,
                              void* d_out, int out_size, void* d_ws, size_t ws_size,
                              hipStream_t stream) {
  const float* locs_l  = (const float*)d_in[0];
  const float* locs_r  = (const float*)d_in[1];
  const float* verts_l = (const float*)d_in[2];
  const float* verts_r = (const float*)d_in[3];
  const float* feats_l = (const float*)d_in[4];
  const float* feats_r = (const float*)d_in[5];
  const float* w1 = (const float*)d_in[6];
  const float* b1 = (const float*)d_in[7];
  const float* w2 = (const float*)d_in[8];
  const float* b2 = (const float*)d_in[9];

  char* ws = (char*)d_ws;
  uint16_t* fT = (uint16_t*)ws;                               // 16 MiB
  float*    vS = (float*)(ws + 16777216);                     // 2 MiB
  float*    xb = (float*)(ws + 16777216 + 2097152);           // 8.125 MiB
  float*   out = (float*)d_out;

  pre_kernel<<<1024, 256, 0, stream>>>(verts_l, verts_r, feats_l, feats_r, fT, vS);
  interp_kernel<<<512, 256, 0, stream>>>(locs_l, locs_r, fT, vS, xb);
  mlp_kernel<<<1024, 256, 0, stream>>>(xb, w1, b1, w2, b2, out);
}

// Round 3
// 251.869 us; speedup vs baseline: 2.7018x; 2.7018x over previous
//
#include <hip/hip_runtime.h>
#include <hip/hip_bf16.h>
#include <stdint.h>

#define B_ 8
#define L_ 2048
#define V_ 8192
#define C_ 64
#define F_ 130   // 2*(C+1)

typedef float    f32x4  __attribute__((ext_vector_type(4)));
typedef float    f32x2  __attribute__((ext_vector_type(2)));
typedef short    s16x8  __attribute__((ext_vector_type(8)));
typedef __bf16   bf16x8 __attribute__((ext_vector_type(8)));
typedef uint32_t u32x4  __attribute__((ext_vector_type(4)));

#if __has_builtin(__builtin_amdgcn_exp2f)
#define EXP2(x) __builtin_amdgcn_exp2f(x)
#else
#define EXP2(x) exp2f(x)
#endif

__device__ __forceinline__ uint32_t pack2bf(float a, float b) {
  uint16_t ua = __builtin_bit_cast(uint16_t, (__bf16)a);
  uint16_t ub = __builtin_bit_cast(uint16_t, (__bf16)b);
  return (uint32_t)ua | ((uint32_t)ub << 16);
}

__device__ __forceinline__ float wave_sum(float v) {
  v += __shfl_xor(v, 1);  v += __shfl_xor(v, 2);  v += __shfl_xor(v, 4);
  v += __shfl_xor(v, 8);  v += __shfl_xor(v, 16); v += __shfl_xor(v, 32);
  return v;
}

// async global->LDS, 16B per lane: lds dest = wave-uniform base + lane*16
__device__ __forceinline__ void gload_lds16(const void* g, void* l) {
  __builtin_amdgcn_global_load_lds(
      (const __attribute__((address_space(1))) void*)g,
      (__attribute__((address_space(3))) void*)l, 16, 0, 0);
}

// ---------------------------------------------------------------------------
// PRE: blocks [0,512): feats -> bf16, packed into PRE-SWIZZLED 8KB k-tiles:
//   fT2[p][ktile][8192B], tile byte for (ch,kq) = ch*128 + ((kq*16)^((ch&7)<<4))
//   holding bf16 feats[v = ktile*64 + kq*8 + e][ch].
//   Thread t' in [0,64): ch=t'>>3, kq=(t'&7)^(ch&7)  =>  dst byte = t'*16
//   (swizzle cancels -> perfectly coalesced 16B writes).
// blocks [512,1024): verts -> vS2[p][ktile][comp(x,y,z,n2)][64] (1KB tiles)
// p = side*8 + b
// ---------------------------------------------------------------------------
__global__ __launch_bounds__(256) void pre_kernel(
    const float* __restrict__ verts_l, const float* __restrict__ verts_r,
    const float* __restrict__ feats_l, const float* __restrict__ feats_r,
    uint16_t* __restrict__ fT2, float* __restrict__ vS2)
{
  const int blk = blockIdx.x, tid = threadIdx.x;
  if (blk < 512) {
    const int p = blk >> 5, kt4 = blk & 31;
    const int side = p >> 3, bb = p & 7;
    const float* src = (side ? feats_r : feats_l) + (size_t)bb * (V_ * C_);
    const int sub = tid >> 6, t = tid & 63;
    const int ktile = kt4 * 4 + sub;
    const int ch = t >> 3;
    const int kq = (t & 7) ^ (ch & 7);
    const int k0 = ktile * 64 + kq * 8;
    float f[8];
    #pragma unroll
    for (int e = 0; e < 8; ++e) f[e] = src[(size_t)(k0 + e) * C_ + ch];
    u32x4 val = { pack2bf(f[0], f[1]), pack2bf(f[2], f[3]),
                  pack2bf(f[4], f[5]), pack2bf(f[6], f[7]) };
    char* dst = (char*)fT2 + ((size_t)p * 128 + ktile) * 8192 + t * 16;
    *(u32x4*)dst = val;
  } else {
    const int blk2 = blk - 512;
    const int p = blk2 >> 5, chunk = blk2 & 31;
    const int side = p >> 3, bb = p & 7;
    const float* src = (side ? verts_r : verts_l) + (size_t)bb * (V_ * 3);
    const int v = chunk * 256 + tid;
    const float x = src[v * 3 + 0], y = src[v * 3 + 1], z = src[v * 3 + 2];
    const float n2 = x * x + y * y + z * z;
    float* d = vS2 + (size_t)p * 32768 + (size_t)(v >> 6) * 256 + (v & 63);
    d[0] = x; d[64] = y; d[128] = z; d[192] = n2;
  }
}

// ---------------------------------------------------------------------------
// FUSED interp(both sides) + MLP.
// Grid 256 = 8 batches x 32 row-tiles; bb = bid&7 pins batch -> XCD (L2 reuse).
// Block: 512 thr = 8 waves: (rowgrp g = wid&3) x (k-half h = wid>>2).
// Per side: K-loop 128 x 64-vert tiles, global_load_lds double-buffered;
// each wave: 16 rows x 32 k of exp(-d/sigma) in regs -> bf16 A-frag,
// 4x mfma_f32_16x16x32_bf16 over 64 channels. K-halves merged via LDS xs,
// normalized by dens; then in-block fp32 MLP (w1 from L2, x broadcast LDS).
// ---------------------------------------------------------------------------
__global__ __launch_bounds__(512, 2) void fused_kernel(
    const float* __restrict__ locs_l, const float* __restrict__ locs_r,
    const uint16_t* __restrict__ fT2, const float* __restrict__ vS2,
    const float* __restrict__ w1, const float* __restrict__ b1,
    const float* __restrict__ w2, const float* __restrict__ b2,
    float* __restrict__ outp)
{
  __shared__ __align__(16) char  flds[2][8192];
  __shared__ __align__(16) float vlds[2][4][64];
  __shared__ __align__(16) float xs[64][136];   // [row][0..129] concat x, pitch 136
  __shared__ float densp[64];

  const int bid  = blockIdx.x;
  const int bb   = bid & 7;          // batch -> XCD
  const int tile = bid >> 3;         // 0..31
  const int tid  = threadIdx.x;
  const int wid  = tid >> 6, lane = tid & 63;
  const int g    = wid & 3, h = wid >> 2;
  const int ln15 = lane & 15, lg = lane >> 4;
  const int xorv = (ln15 & 7) << 4;
  constexpr float KEXP = -0.57707801635558535f;  // -1/(2.5*ln2)

  for (int s = 0; s < 2; ++s) {
    const int p = s * 8 + bb;
    const float* locs = (s ? locs_r : locs_l) + (size_t)bb * (L_ * 3);
    const int arow = tile * 64 + g * 16 + ln15;
    const float px = locs[arow * 3 + 0];
    const float py = locs[arow * 3 + 1];
    const float pz = locs[arow * 3 + 2];
    const float pn2 = px * px + py * py + pz * pz;

    const char* ftp = (const char*)fT2 + (size_t)p * (128 * 8192);
    const char* vtp = (const char*)vS2 + (size_t)p * (128 * 1024);

    f32x4 acc0 = {0.f,0.f,0.f,0.f}, acc1 = {0.f,0.f,0.f,0.f};
    f32x4 acc2 = {0.f,0.f,0.f,0.f}, acc3 = {0.f,0.f,0.f,0.f};
    float dens = 0.f;

    // prologue: stage tile 0 into buffer 0
    gload_lds16(ftp + wid * 1024 + lane * 16, &flds[0][wid * 1024]);
    if (wid == 0) gload_lds16(vtp + lane * 16, &vlds[0][0][0]);
    __syncthreads();

    for (int kt = 0; kt < 128; ++kt) {
      const int cur = kt & 1;
      if (kt < 127) {   // issue next-tile loads first; land by barrier drain
        const int nxt = cur ^ 1;
        gload_lds16(ftp + (size_t)(kt + 1) * 8192 + wid * 1024 + lane * 16,
                    &flds[nxt][wid * 1024]);
        if (wid == 0)
          gload_lds16(vtp + (size_t)(kt + 1) * 1024 + lane * 16, &vlds[nxt][0][0]);
      }
      const int kof = h * 32 + lg * 8;
      const f32x4 vx0 = *(const f32x4*)&vlds[cur][0][kof];
      const f32x4 vx1 = *(const f32x4*)&vlds[cur][0][kof + 4];
      const f32x4 vy0 = *(const f32x4*)&vlds[cur][1][kof];
      const f32x4 vy1 = *(const f32x4*)&vlds[cur][1][kof + 4];
      const f32x4 vz0 = *(const f32x4*)&vlds[cur][2][kof];
      const f32x4 vz1 = *(const f32x4*)&vlds[cur][2][kof + 4];
      const f32x4 vn0 = *(const f32x4*)&vlds[cur][3][kof];
      const f32x4 vn1 = *(const f32x4*)&vlds[cur][3][kof + 4];
      bf16x8 av;
      #pragma unroll
      for (int e = 0; e < 8; ++e) {
        const float vx = (e < 4) ? vx0[e] : vx1[e - 4];
        const float vy = (e < 4) ? vy0[e] : vy1[e - 4];
        const float vz = (e < 4) ? vz0[e] : vz1[e - 4];
        const float vn = (e < 4) ? vn0[e] : vn1[e - 4];
        const float t2 = fmaf(px, vx, fmaf(py, vy, pz * vz));
        const float d2 = fmaf(-2.f, t2, pn2 + vn);
        const float d  = __builtin_amdgcn_sqrtf(fmaxf(d2, 0.f));
        const float w  = EXP2(d * KEXP);
        dens += w;
        av[e] = (__bf16)w;
      }
      const s16x8 afrag = __builtin_bit_cast(s16x8, av);
      const char* fl = flds[cur];
      const int ab = ln15 * 128 + (((h << 6) | (lg << 4)) ^ xorv);
      const s16x8 bf0 = *(const s16x8*)(fl + ab);
      const s16x8 bf1 = *(const s16x8*)(fl + ab + 2048);
      const s16x8 bf2 = *(const s16x8*)(fl + ab + 4096);
      const s16x8 bf3 = *(const s16x8*)(fl + ab + 6144);
      acc0 = __builtin_amdgcn_mfma_f32_16x16x32_bf16(afrag, bf0, acc0, 0, 0, 0);
      acc1 = __builtin_amdgcn_mfma_f32_16x16x32_bf16(afrag, bf1, acc1, 0, 0, 0);
      acc2 = __builtin_amdgcn_mfma_f32_16x16x32_bf16(afrag, bf2, acc2, 0, 0, 0);
      acc3 = __builtin_amdgcn_mfma_f32_16x16x32_bf16(afrag, bf3, acc3, 0, 0, 0);
      __syncthreads();
    }

    // combine k-groups within wave: lane -> full half-dens of row (lane&15)
    dens += __shfl_xor(dens, 16);
    dens += __shfl_xor(dens, 32);

    // merge the two K-halves through xs (h=0 writes, h=1 adds)
    if (h == 0) {
      if (lane < 16) densp[g * 16 + lane] = dens;
      #pragma unroll
      for (int r = 0; r < 4; ++r) {
        const int row = g * 16 + lg * 4 + r;
        xs[row][s * 65 +      ln15] = acc0[r];
        xs[row][s * 65 + 16 + ln15] = acc1[r];
        xs[row][s * 65 + 32 + ln15] = acc2[r];
        xs[row][s * 65 + 48 + ln15] = acc3[r];
      }
    }
    __syncthreads();
    if (h == 1) {
      if (lane < 16) densp[g * 16 + lane] += dens;
      #pragma unroll
      for (int r = 0; r < 4; ++r) {
        const int row = g * 16 + lg * 4 + r;
        xs[row][s * 65 +      ln15] += acc0[r];
        xs[row][s * 65 + 16 + ln15] += acc1[r];
        xs[row][s * 65 + 32 + ln15] += acc2[r];
        xs[row][s * 65 + 48 + ln15] += acc3[r];
      }
    }
    __syncthreads();
    // normalize by dens; col 64 holds raw dens (reference concat)
    for (int idx = tid; idx < 64 * 64; idx += 512) {
      const int row = idx >> 6, c = idx & 63;
      xs[row][s * 65 + c] *= (1.0f / densp[row]);
    }
    if (tid < 64) xs[tid][s * 65 + 64] = densp[tid];
    __syncthreads();
  }

  // -------------------- in-block MLP (fp32) --------------------
  const int r0 = wid * 8;                     // 8 rows per wave
  float hh0[8], hh1[8];
  #pragma unroll
  for (int r = 0; r < 8; ++r) { hh0[r] = 0.f; hh1[r] = 0.f; }
  const float* wr0 = w1 + (size_t)lane * F_;
  const float* wr1 = w1 + (size_t)(lane + 64) * F_;

  #pragma unroll 4
  for (int i = 0; i < 128; i += 4) {
    const f32x2 a01 = *(const f32x2*)&wr0[i];
    const f32x2 a23 = *(const f32x2*)&wr0[i + 2];
    const f32x2 c01 = *(const f32x2*)&wr1[i];
    const f32x2 c23 = *(const f32x2*)&wr1[i + 2];
    #pragma unroll
    for (int r = 0; r < 8; ++r) {
      const f32x4 xv = *(const f32x4*)&xs[r0 + r][i];
      hh0[r] = fmaf(xv.x, a01.x, hh0[r]); hh0[r] = fmaf(xv.y, a01.y, hh0[r]);
      hh0[r] = fmaf(xv.z, a23.x, hh0[r]); hh0[r] = fmaf(xv.w, a23.y, hh0[r]);
      hh1[r] = fmaf(xv.x, c01.x, hh1[r]); hh1[r] = fmaf(xv.y, c01.y, hh1[r]);
      hh1[r] = fmaf(xv.z, c23.x, hh1[r]); hh1[r] = fmaf(xv.w, c23.y, hh1[r]);
    }
  }
  { // i-tail: 128,129
    const float a0 = wr0[128], a1 = wr0[129];
    const float c0 = wr1[128], c1 = wr1[129];
    #pragma unroll
    for (int r = 0; r < 8; ++r) {
      const float x0 = xs[r0 + r][128], x1 = xs[r0 + r][129];
      hh0[r] = fmaf(x0, a0, fmaf(x1, a1, hh0[r]));
      hh1[r] = fmaf(x0, c0, fmaf(x1, c1, hh1[r]));
    }
  }
  // j-tail: hidden cols 128,129 via per-row wave reduce
  const float* wr2 = w1 + 128 * F_;
  const float* wr3 = w1 + 129 * F_;
  float hp2[8], hp3[8];
  #pragma unroll
  for (int r = 0; r < 8; ++r) {
    const float xa = xs[r0 + r][lane];
    const float xb = xs[r0 + r][lane + 64];
    float p2 = wr2[lane] * xa + wr2[lane + 64] * xb;
    float p3 = wr3[lane] * xa + wr3[lane + 64] * xb;
    if (lane < 2) {
      const float xc = xs[r0 + r][128 + lane];
      p2 += wr2[128 + lane] * xc;
      p3 += wr3[128 + lane] * xc;
    }
    hp2[r] = wave_sum(p2);
    hp3[r] = wave_sum(p3);
  }
  const float b1a = b1[lane], b1b = b1[lane + 64];
  const float w2a = w2[lane], w2b = w2[lane + 64];
  const float b1c = b1[128], b1d = b1[129];
  const float w2c = w2[128], w2d = w2[129];
  const float b2v = b2[0];
  #pragma unroll
  for (int r = 0; r < 8; ++r) {
    float o = w2a * fmaxf(hh0[r] + b1a, 0.f) + w2b * fmaxf(hh1[r] + b1b, 0.f);
    o = wave_sum(o);
    if (lane == 0) {
      o += w2c * fmaxf(hp2[r] + b1c, 0.f) + w2d * fmaxf(hp3[r] + b1d, 0.f);
      outp[(size_t)bb * L_ + tile * 64 + r0 + r] = o + b2v;
    }
  }
}

// ---------------------------------------------------------------------------
extern "C" void kernel_launch(void* const* d_in, const int* in_sizes, int n_in,
                              void* d_out, int out_size, void* d_ws, size_t ws_size,
                              hipStream_t stream) {
  const float* locs_l  = (const float*)d_in[0];
  const float* locs_r  = (const float*)d_in[1];
  const float* verts_l = (const float*)d_in[2];
  const float* verts_r = (const float*)d_in[3];
  const float* feats_l = (const float*)d_in[4];
  const float* feats_r = (const float*)d_in[5];
  const float* w1 = (const float*)d_in[6];
  const float* b1 = (const float*)d_in[7];
  const float* w2 = (const float*)d_in[8];
  const float* b2 = (const float*)d_in[9];

  char* ws = (char*)d_ws;
  uint16_t* fT2 = (uint16_t*)ws;                 // 16 MiB swizzled feat tiles
  float*    vS2 = (float*)(ws + 16777216);       // 2 MiB vert tiles
  float*    out = (float*)d_out;

  pre_kernel<<<1024, 256, 0, stream>>>(verts_l, verts_r, feats_l, feats_r, fT2, vS2);
  fused_kernel<<<256, 512, 0, stream>>>(locs_l, locs_r, fT2, vS2,
                                        w1, b1, w2, b2, out);
}

// Round 4
// 224.997 us; speedup vs baseline: 3.0245x; 1.1194x over previous
//
#include <hip/hip_runtime.h>
#include <hip/hip_bf16.h>
#include <stdint.h>

#define B_ 8
#define L_ 2048
#define V_ 8192
#define C_ 64
#define F_ 130   // 2*(C+1)

typedef float    f32x4  __attribute__((ext_vector_type(4)));
typedef float    f32x2  __attribute__((ext_vector_type(2)));
typedef short    s16x8  __attribute__((ext_vector_type(8)));
typedef __bf16   bf16x8 __attribute__((ext_vector_type(8)));
typedef uint32_t u32x4  __attribute__((ext_vector_type(4)));

#if __has_builtin(__builtin_amdgcn_exp2f)
#define EXP2(x) __builtin_amdgcn_exp2f(x)
#else
#define EXP2(x) exp2f(x)
#endif

#if __has_builtin(__builtin_elementwise_fma)
#define PK_FMA(a,b,c) __builtin_elementwise_fma((a),(b),(c))
#else
__device__ __forceinline__ f32x2 PK_FMA(f32x2 a, f32x2 b, f32x2 c) {
  f32x2 r; r.x = fmaf(a.x,b.x,c.x); r.y = fmaf(a.y,b.y,c.y); return r;
}
#endif
#if __has_builtin(__builtin_elementwise_max)
#define PK_MAX(a,b) __builtin_elementwise_max((a),(b))
#else
__device__ __forceinline__ f32x2 PK_MAX(f32x2 a, f32x2 b) {
  f32x2 r; r.x = fmaxf(a.x,b.x); r.y = fmaxf(a.y,b.y); return r;
}
#endif

__device__ __forceinline__ uint32_t pack2bf(float a, float b) {
  uint16_t ua = __builtin_bit_cast(uint16_t, (__bf16)a);
  uint16_t ub = __builtin_bit_cast(uint16_t, (__bf16)b);
  return (uint32_t)ua | ((uint32_t)ub << 16);
}

__device__ __forceinline__ float wave_sum(float v) {
  v += __shfl_xor(v, 1);  v += __shfl_xor(v, 2);  v += __shfl_xor(v, 4);
  v += __shfl_xor(v, 8);  v += __shfl_xor(v, 16); v += __shfl_xor(v, 32);
  return v;
}

// async global->LDS, 16B per lane: lds dest = wave-uniform base + lane*16
__device__ __forceinline__ void gload_lds16(const void* g, void* l) {
  __builtin_amdgcn_global_load_lds(
      (const __attribute__((address_space(1))) void*)g,
      (__attribute__((address_space(3))) void*)l, 16, 0, 0);
}

// ---------------------------------------------------------------------------
// PRE (coalesced): blocks [0,1024): feats -> bf16 pre-swizzled 8KB k-tiles.
//   Block = (p, ktile-pair). Per 64v subtile: stage [64v][64ch] fp32 via LDS
//   (pitch 68 -> <=2-way read conflicts), gather-swizzle, write bf16 packed.
//   Tile byte for (ch,kq) = ch*128 + ((kq^(ch&7))<<4); role r in [0,64):
//   ch=r>>3, kq=(r&7)^(ch&7) => byte r*16 (coalesced).
// blocks [1024,1536): verts -> vS2[p][ktile][{x,y,z,n2}][64] (1KB tiles)
// ---------------------------------------------------------------------------
__global__ __launch_bounds__(256) void pre_kernel(
    const float* __restrict__ verts_l, const float* __restrict__ verts_r,
    const float* __restrict__ feats_l, const float* __restrict__ feats_r,
    uint16_t* __restrict__ fT2, float* __restrict__ vS2)
{
  __shared__ float fs[64][68];
  const int blk = blockIdx.x, tid = threadIdx.x;
  if (blk < 1024) {
    const int p = blk >> 6, kt2 = blk & 63;      // ktiles 2*kt2, 2*kt2+1
    const int side = p >> 3, bb = p & 7;
    const float* src = (side ? feats_r : feats_l) + (size_t)bb * (V_ * C_);
    const int r  = tid & 63;                      // gather role
    const int eq = tid >> 6;                      // e-quad 0..3
    const int ch = r >> 3;
    const int kq = (r & 7) ^ (ch & 7);
    #pragma unroll
    for (int sub = 0; sub < 2; ++sub) {
      const int ktile = kt2 * 2 + sub;
      const int v0 = ktile * 64;
      { // stage 64 rows x 64 ch, coalesced: thread t -> row t>>2, 16 cols
        const int sv = tid >> 2, c0 = (tid & 3) * 16;
        const float* s = src + (size_t)(v0 + sv) * C_ + c0;
        f32x4 a = *(const f32x4*)(s);
        f32x4 b = *(const f32x4*)(s + 4);
        f32x4 c = *(const f32x4*)(s + 8);
        f32x4 d = *(const f32x4*)(s + 12);
        *(f32x4*)&fs[sv][c0]      = a;
        *(f32x4*)&fs[sv][c0 + 4]  = b;
        *(f32x4*)&fs[sv][c0 + 8]  = c;
        *(f32x4*)&fs[sv][c0 + 12] = d;
      }
      __syncthreads();
      { // gather-swizzle: thread handles 2 elements (e = eq*2, eq*2+1)
        const int e = eq * 2;
        const float f0 = fs[kq * 8 + e][ch];
        const float f1 = fs[kq * 8 + e + 1][ch];
        char* dst = (char*)fT2 + ((size_t)p * 128 + ktile) * 8192 + r * 16 + eq * 4;
        *(uint32_t*)dst = pack2bf(f0, f1);
      }
      __syncthreads();
    }
  } else {
    const int blk2 = blk - 1024;
    const int p = blk2 >> 5, chunk = blk2 & 31;
    const int side = p >> 3, bb = p & 7;
    const float* src = (side ? verts_r : verts_l) + (size_t)bb * (V_ * 3);
    const int v = chunk * 256 + tid;
    const float x = src[v * 3 + 0], y = src[v * 3 + 1], z = src[v * 3 + 2];
    const float n2 = x * x + y * y + z * z;
    float* d = vS2 + (size_t)p * 32768 + (size_t)(v >> 6) * 256 + (v & 63);
    d[0] = x; d[64] = y; d[128] = z; d[192] = n2;
  }
}

// ---------------------------------------------------------------------------
// FUSED interp(both sides) + MLP.
// Grid 512 = 8 batches x 64 row-tiles(32 rows); bb = bid&7 pins batch -> XCD.
// Block: 512 thr = 8 waves: rowgrp g = wid&1 (16 rows) x k-quarter h = wid>>1.
// K-loop: 64 iters x 128-vert tiles (2x 8KB swizzled subtiles), double-buffered
// global_load_lds. Per iter per wave: 16 rows x 32 verts of w = exp(-d/sigma)
// via packed-f32 math -> bf16 A-frag, 4x mfma 16x16x32 over 64 channels.
// 4 k-quarters merged via xs phases; then in-block fp32 MLP.
// 2 blocks/CU (LDS 54.4KB) -> 16 waves/CU.
// ---------------------------------------------------------------------------
__global__ __launch_bounds__(512, 4) void fused_kernel(
    const float* __restrict__ locs_l, const float* __restrict__ locs_r,
    const uint16_t* __restrict__ fT2, const float* __restrict__ vS2,
    const float* __restrict__ w1, const float* __restrict__ b1,
    const float* __restrict__ w2, const float* __restrict__ b2,
    float* __restrict__ outp)
{
  __shared__ __align__(16) char  flds[2][16384];      // 2 x (2 subtiles x 8KB)
  __shared__ __align__(16) float vlds[2][2][4][64];   // [buf][sub][comp][v]
  __shared__ __align__(16) float xs[32][136];
  __shared__ float densp[32];

  const int bid  = blockIdx.x;
  const int bb   = bid & 7;
  const int tile = bid >> 3;          // 0..63
  const int tid  = threadIdx.x;
  const int wid  = tid >> 6, lane = tid & 63;
  const int g    = wid & 1, h = wid >> 1;      // h in [0,4): 32-vert quarter
  const int ln15 = lane & 15, lg = lane >> 4;
  const int xorv = (ln15 & 7) << 4;
  constexpr float KEXP = -0.57707801635558535f;  // -1/(2.5*ln2)
  const f32x2 kexpv = {KEXP, KEXP};
  const f32x2 m2v   = {-2.f, -2.f};
  const f32x2 zerov = {0.f, 0.f};

  const int sub  = h >> 1;            // which 8KB subtile
  const int hh   = h & 1;             // 32-vert half within subtile
  const int abfix = sub * 8192 + ln15 * 128 + ((((hh << 2) | lg) << 4) ^ xorv);

  for (int s = 0; s < 2; ++s) {
    const int p = s * 8 + bb;
    const float* locs = (s ? locs_r : locs_l) + (size_t)bb * (L_ * 3);
    const int arow = tile * 32 + g * 16 + ln15;
    const float px = locs[arow * 3 + 0];
    const float py = locs[arow * 3 + 1];
    const float pz = locs[arow * 3 + 2];
    const float pn2 = px * px + py * py + pz * pz;
    const f32x2 pxv = {px, px}, pyv = {py, py}, pzv = {pz, pz};
    const f32x2 pn2v = {pn2, pn2};

    const char* ftp = (const char*)fT2 + (size_t)p * (128 * 8192);
    const char* vtp = (const char*)vS2 + (size_t)p * (128 * 1024);

    f32x4 acc0 = {0.f,0.f,0.f,0.f}, acc1 = {0.f,0.f,0.f,0.f};
    f32x4 acc2 = {0.f,0.f,0.f,0.f}, acc3 = {0.f,0.f,0.f,0.f};
    f32x2 densv = {0.f, 0.f};

    // prologue: stage 128-vert tile 0
    gload_lds16(ftp + wid * 2048 + lane * 16,        &flds[0][wid * 2048]);
    gload_lds16(ftp + wid * 2048 + 1024 + lane * 16, &flds[0][wid * 2048 + 1024]);
    if (wid < 2) gload_lds16(vtp + wid * 1024 + lane * 16, &vlds[0][wid][0][0]);
    __syncthreads();

    for (int kt = 0; kt < 64; ++kt) {
      const int cur = kt & 1;
      if (kt < 63) {   // issue next-tile loads first; land by barrier drain
        const int nxt = cur ^ 1;
        const char* gf = ftp + (size_t)(kt + 1) * 16384 + wid * 2048;
        gload_lds16(gf + lane * 16,        &flds[nxt][wid * 2048]);
        gload_lds16(gf + 1024 + lane * 16, &flds[nxt][wid * 2048 + 1024]);
        if (wid < 2)
          gload_lds16(vtp + (size_t)(kt + 1) * 2048 + wid * 1024 + lane * 16,
                      &vlds[nxt][wid][0][0]);
      }
      const int kof = hh * 32 + lg * 8;
      const f32x4 vx0 = *(const f32x4*)&vlds[cur][sub][0][kof];
      const f32x4 vx1 = *(const f32x4*)&vlds[cur][sub][0][kof + 4];
      const f32x4 vy0 = *(const f32x4*)&vlds[cur][sub][1][kof];
      const f32x4 vy1 = *(const f32x4*)&vlds[cur][sub][1][kof + 4];
      const f32x4 vz0 = *(const f32x4*)&vlds[cur][sub][2][kof];
      const f32x4 vz1 = *(const f32x4*)&vlds[cur][sub][2][kof + 4];
      const f32x4 vn0 = *(const f32x4*)&vlds[cur][sub][3][kof];
      const f32x4 vn1 = *(const f32x4*)&vlds[cur][sub][3][kof + 4];
      bf16x8 av;
      #pragma unroll
      for (int pr = 0; pr < 4; ++pr) {
        const f32x4 sx = (pr < 2) ? vx0 : vx1;
        const f32x4 sy = (pr < 2) ? vy0 : vy1;
        const f32x4 sz = (pr < 2) ? vz0 : vz1;
        const f32x4 sn = (pr < 2) ? vn0 : vn1;
        const int o = (pr & 1) * 2;
        const f32x2 vx = {sx[o], sx[o + 1]};
        const f32x2 vy = {sy[o], sy[o + 1]};
        const f32x2 vz = {sz[o], sz[o + 1]};
        const f32x2 vn = {sn[o], sn[o + 1]};
        f32x2 t  = PK_FMA(pyv, vy, pzv * vz);
        t        = PK_FMA(pxv, vx, t);
        f32x2 d2 = PK_FMA(m2v, t, pn2v + vn);
        d2       = PK_MAX(d2, zerov);
        f32x2 dd;
        dd.x = __builtin_amdgcn_sqrtf(d2.x);
        dd.y = __builtin_amdgcn_sqrtf(d2.y);
        dd = dd * kexpv;
        const float w0 = EXP2(dd.x);
        const float w1v = EXP2(dd.y);
        densv += (f32x2){w0, w1v};
        av[pr * 2]     = (__bf16)w0;
        av[pr * 2 + 1] = (__bf16)w1v;
      }
      const s16x8 afrag = __builtin_bit_cast(s16x8, av);
      const char* fl = flds[cur];
      const s16x8 bf0 = *(const s16x8*)(fl + abfix);
      const s16x8 bf1 = *(const s16x8*)(fl + abfix + 2048);
      const s16x8 bf2 = *(const s16x8*)(fl + abfix + 4096);
      const s16x8 bf3 = *(const s16x8*)(fl + abfix + 6144);
      acc0 = __builtin_amdgcn_mfma_f32_16x16x32_bf16(afrag, bf0, acc0, 0, 0, 0);
      acc1 = __builtin_amdgcn_mfma_f32_16x16x32_bf16(afrag, bf1, acc1, 0, 0, 0);
      acc2 = __builtin_amdgcn_mfma_f32_16x16x32_bf16(afrag, bf2, acc2, 0, 0, 0);
      acc3 = __builtin_amdgcn_mfma_f32_16x16x32_bf16(afrag, bf3, acc3, 0, 0, 0);
      __syncthreads();
    }

    // lane -> quarter-dens of row (lane&15)
    float dens = densv.x + densv.y;
    dens += __shfl_xor(dens, 16);
    dens += __shfl_xor(dens, 32);

    // merge 4 k-quarters through xs (phase h==0 writes, 1..3 add)
    #pragma unroll
    for (int ph = 0; ph < 4; ++ph) {
      if (h == ph) {
        if (ph == 0) {
          if (lane < 16) densp[g * 16 + lane] = dens;
          #pragma unroll
          for (int r = 0; r < 4; ++r) {
            const int row = g * 16 + lg * 4 + r;
            xs[row][s * 65 +      ln15] = acc0[r];
            xs[row][s * 65 + 16 + ln15] = acc1[r];
            xs[row][s * 65 + 32 + ln15] = acc2[r];
            xs[row][s * 65 + 48 + ln15] = acc3[r];
          }
        } else {
          if (lane < 16) densp[g * 16 + lane] += dens;
          #pragma unroll
          for (int r = 0; r < 4; ++r) {
            const int row = g * 16 + lg * 4 + r;
            xs[row][s * 65 +      ln15] += acc0[r];
            xs[row][s * 65 + 16 + ln15] += acc1[r];
            xs[row][s * 65 + 32 + ln15] += acc2[r];
            xs[row][s * 65 + 48 + ln15] += acc3[r];
          }
        }
      }
      __syncthreads();
    }
    // normalize by dens; col 64 holds raw dens
    for (int idx = tid; idx < 32 * 64; idx += 512) {
      const int row = idx >> 6, c = idx & 63;
      xs[row][s * 65 + c] *= (1.0f / densp[row]);
    }
    if (tid < 32) xs[tid][s * 65 + 64] = densp[tid];
    __syncthreads();
  }

  // -------------------- in-block MLP (fp32) --------------------
  const int r0 = wid * 4;                     // 4 rows per wave
  float hh0[4] = {0.f,0.f,0.f,0.f}, hh1[4] = {0.f,0.f,0.f,0.f};
  const float* wr0 = w1 + (size_t)lane * F_;
  const float* wr1 = w1 + (size_t)(lane + 64) * F_;

  #pragma unroll 4
  for (int i = 0; i < 128; i += 4) {
    const f32x2 a01 = *(const f32x2*)&wr0[i];
    const f32x2 a23 = *(const f32x2*)&wr0[i + 2];
    const f32x2 c01 = *(const f32x2*)&wr1[i];
    const f32x2 c23 = *(const f32x2*)&wr1[i + 2];
    #pragma unroll
    for (int r = 0; r < 4; ++r) {
      const f32x4 xv = *(const f32x4*)&xs[r0 + r][i];
      hh0[r] = fmaf(xv.x, a01.x, hh0[r]); hh0[r] = fmaf(xv.y, a01.y, hh0[r]);
      hh0[r] = fmaf(xv.z, a23.x, hh0[r]); hh0[r] = fmaf(xv.w, a23.y, hh0[r]);
      hh1[r] = fmaf(xv.x, c01.x, hh1[r]); hh1[r] = fmaf(xv.y, c01.y, hh1[r]);
      hh1[r] = fmaf(xv.z, c23.x, hh1[r]); hh1[r] = fmaf(xv.w, c23.y, hh1[r]);
    }
  }
  { // i-tail: 128,129
    const float a0 = wr0[128], a1 = wr0[129];
    const float c0 = wr1[128], c1 = wr1[129];
    #pragma unroll
    for (int r = 0; r < 4; ++r) {
      const float x0 = xs[r0 + r][128], x1 = xs[r0 + r][129];
      hh0[r] = fmaf(x0, a0, fmaf(x1, a1, hh0[r]));
      hh1[r] = fmaf(x0, c0, fmaf(x1, c1, hh1[r]));
    }
  }
  // j-tail: hidden cols 128,129 via per-row wave reduce
  const float* wr2 = w1 + 128 * F_;
  const float* wr3 = w1 + 129 * F_;
  float hp2[4], hp3[4];
  #pragma unroll
  for (int r = 0; r < 4; ++r) {
    const float xa = xs[r0 + r][lane];
    const float xb = xs[r0 + r][lane + 64];
    float p2 = wr2[lane] * xa + wr2[lane + 64] * xb;
    float p3 = wr3[lane] * xa + wr3[lane + 64] * xb;
    if (lane < 2) {
      const float xc = xs[r0 + r][128 + lane];
      p2 += wr2[128 + lane] * xc;
      p3 += wr3[128 + lane] * xc;
    }
    hp2[r] = wave_sum(p2);
    hp3[r] = wave_sum(p3);
  }
  const float b1a = b1[lane], b1b = b1[lane + 64];
  const float w2a = w2[lane], w2b = w2[lane + 64];
  const float b1c = b1[128], b1d = b1[129];
  const float w2c = w2[128], w2d = w2[129];
  const float b2v = b2[0];
  #pragma unroll
  for (int r = 0; r < 4; ++r) {
    float o = w2a * fmaxf(hh0[r] + b1a, 0.f) + w2b * fmaxf(hh1[r] + b1b, 0.f);
    o = wave_sum(o);
    if (lane == 0) {
      o += w2c * fmaxf(hp2[r] + b1c, 0.f) + w2d * fmaxf(hp3[r] + b1d, 0.f);
      outp[(size_t)bb * L_ + tile * 32 + r0 + r] = o + b2v;
    }
  }
}

// ---------------------------------------------------------------------------
extern "C" void kernel_launch(void* const* d_in, const int* in_sizes, int n_in,
                              void* d_out, int out_size, void* d_ws, size_t ws_size,
                              hipStream_t stream) {
  const float* locs_l  = (const float*)d_in[0];
  const float* locs_r  = (const float*)d_in[1];
  const float* verts_l = (const float*)d_in[2];
  const float* verts_r = (const float*)d_in[3];
  const float* feats_l = (const float*)d_in[4];
  const float* feats_r = (const float*)d_in[5];
  const float* w1 = (const float*)d_in[6];
  const float* b1 = (const float*)d_in[7];
  const float* w2 = (const float*)d_in[8];
  const float* b2 = (const float*)d_in[9];

  char* ws = (char*)d_ws;
  uint16_t* fT2 = (uint16_t*)ws;                 // 16 MiB swizzled feat tiles
  float*    vS2 = (float*)(ws + 16777216);       // 2 MiB vert tiles
  float*    out = (float*)d_out;

  pre_kernel<<<1536, 256, 0, stream>>>(verts_l, verts_r, feats_l, feats_r, fT2, vS2);
  fused_kernel<<<512, 512, 0, stream>>>(locs_l, locs_r, fT2, vS2,
                                        w1, b1, w2, b2, out);
}

// Round 5
// 223.845 us; speedup vs baseline: 3.0401x; 1.0051x over previous
//
#include <hip/hip_runtime.h>
#include <hip/hip_bf16.h>
#include <stdint.h>

#define B_ 8
#define L_ 2048
#define V_ 8192
#define C_ 64
#define F_ 130   // 2*(C+1)

typedef float    f32x4  __attribute__((ext_vector_type(4)));
typedef float    f32x2  __attribute__((ext_vector_type(2)));
typedef short    s16x8  __attribute__((ext_vector_type(8)));
typedef __bf16   bf16x8 __attribute__((ext_vector_type(8)));
typedef uint32_t u32x4  __attribute__((ext_vector_type(4)));

#if __has_builtin(__builtin_amdgcn_exp2f)
#define EXP2(x) __builtin_amdgcn_exp2f(x)
#else
#define EXP2(x) exp2f(x)
#endif

#if __has_builtin(__builtin_elementwise_fma)
#define PK_FMA4(a,b,c) __builtin_elementwise_fma((a),(b),(c))
#else
__device__ __forceinline__ f32x4 PK_FMA4(f32x4 a, f32x4 b, f32x4 c) {
  f32x4 r; for (int i=0;i<4;++i) r[i]=fmaf(a[i],b[i],c[i]); return r;
}
#endif
#if __has_builtin(__builtin_elementwise_max)
#define PK_MAX4(a,b) __builtin_elementwise_max((a),(b))
#else
__device__ __forceinline__ f32x4 PK_MAX4(f32x4 a, f32x4 b) {
  f32x4 r; for (int i=0;i<4;++i) r[i]=fmaxf(a[i],b[i]); return r;
}
#endif

// K = 1/(2.5*ln2); w = exp(-d/2.5) = exp2(-K*d) = exp2(-sqrt(K^2*d2))
constexpr float KEXP2 = (float)(0.57707801635558535 * 0.57707801635558535);

__device__ __forceinline__ uint32_t pack2bf(float a, float b) {
  uint16_t ua = __builtin_bit_cast(uint16_t, (__bf16)a);
  uint16_t ub = __builtin_bit_cast(uint16_t, (__bf16)b);
  return (uint32_t)ua | ((uint32_t)ub << 16);
}

__device__ __forceinline__ float wave_sum(float v) {
  v += __shfl_xor(v, 1);  v += __shfl_xor(v, 2);  v += __shfl_xor(v, 4);
  v += __shfl_xor(v, 8);  v += __shfl_xor(v, 16); v += __shfl_xor(v, 32);
  return v;
}

// async global->LDS, 16B per lane: lds dest = wave-uniform base + lane*16
__device__ __forceinline__ void gload_lds16(const void* g, void* l) {
  __builtin_amdgcn_global_load_lds(
      (const __attribute__((address_space(1))) void*)g,
      (__attribute__((address_space(3))) void*)l, 16, 0, 0);
}

// ---------------------------------------------------------------------------
// PRE: blocks [0,1024): feats -> bf16 pre-swizzled 8KB k-tiles.
//   Stage [64v][64ch] fp32 in LDS pitch 68 with column XOR-swizzle
//   col' = col ^ (((row>>3)&7)<<3): read of (row=kq*8+e, ch) then hits bank
//   (68e + ch + 8kq) mod 32 -> exactly 2-way (was 8-way: 544*kq = 0 mod 32).
//   Output tile byte for (ch,kq) = ch*128 + ((kq^(ch&7))<<4); thread role
//   r in [0,64): ch=r>>3, kq=(r&7)^(ch&7) => dst byte r*16 (coalesced).
// blocks [1024,1536): verts -> vS2[p][ktile][{x',y',z',n2'}][64], 1KB tiles,
//   PRE-SCALED: x'=-2*K2*x (K2=KEXP2), n2'=K2*|v|^2  => d2' computes in 4 ops.
// ---------------------------------------------------------------------------
__global__ __launch_bounds__(256) void pre_kernel(
    const float* __restrict__ verts_l, const float* __restrict__ verts_r,
    const float* __restrict__ feats_l, const float* __restrict__ feats_r,
    uint16_t* __restrict__ fT2, float* __restrict__ vS2)
{
  __shared__ float fs[64][68];
  const int blk = blockIdx.x, tid = threadIdx.x;
  if (blk < 1024) {
    const int p = blk >> 6, kt2 = blk & 63;      // ktiles 2*kt2, 2*kt2+1
    const int side = p >> 3, bb = p & 7;
    const float* src = (side ? feats_r : feats_l) + (size_t)bb * (V_ * C_);
    const int r  = tid & 63;                      // gather role
    const int eq = tid >> 6;                      // e-pair selector 0..3
    const int ch = r >> 3;
    const int kq = (r & 7) ^ (ch & 7);
    #pragma unroll
    for (int sub = 0; sub < 2; ++sub) {
      const int ktile = kt2 * 2 + sub;
      const int v0 = ktile * 64;
      { // stage 64 rows x 64 ch, coalesced; column XOR-swizzle per 4-col block
        const int sv = tid >> 2, c0 = (tid & 3) * 16;
        const int m = ((sv >> 3) & 7) << 3;
        const float* s = src + (size_t)(v0 + sv) * C_ + c0;
        f32x4 a = *(const f32x4*)(s);
        f32x4 b = *(const f32x4*)(s + 4);
        f32x4 c = *(const f32x4*)(s + 8);
        f32x4 d = *(const f32x4*)(s + 12);
        *(f32x4*)&fs[sv][(c0)      ^ m] = a;
        *(f32x4*)&fs[sv][(c0 + 4)  ^ m] = b;
        *(f32x4*)&fs[sv][(c0 + 8)  ^ m] = c;
        *(f32x4*)&fs[sv][(c0 + 12) ^ m] = d;
      }
      __syncthreads();
      { // gather-swizzle: thread handles e = eq*2, eq*2+1 (same kq row-block)
        const int e = eq * 2;
        const int row0 = kq * 8 + e;
        const int mm = kq << 3;                   // ((row>>3)&7)<<3
        const float f0 = fs[row0][ch ^ mm];
        const float f1 = fs[row0 + 1][ch ^ mm];
        char* dst = (char*)fT2 + ((size_t)p * 128 + ktile) * 8192 + r * 16 + eq * 4;
        *(uint32_t*)dst = pack2bf(f0, f1);
      }
      __syncthreads();
    }
  } else {
    const int blk2 = blk - 1024;
    const int p = blk2 >> 5, chunk = blk2 & 31;
    const int side = p >> 3, bb = p & 7;
    const float* src = (side ? verts_r : verts_l) + (size_t)bb * (V_ * 3);
    const int v = chunk * 256 + tid;
    const float x = src[v * 3 + 0], y = src[v * 3 + 1], z = src[v * 3 + 2];
    const float n2 = x * x + y * y + z * z;
    constexpr float M2K = -2.0f * KEXP2;
    float* d = vS2 + (size_t)p * 32768 + (size_t)(v >> 6) * 256 + (v & 63);
    d[0] = M2K * x; d[64] = M2K * y; d[128] = M2K * z; d[192] = KEXP2 * n2;
  }
}

// ---------------------------------------------------------------------------
// FUSED interp(both sides) + MLP.
// Grid 512 = 8 batches x 64 row-tiles(32 rows); bb = bid&7 pins batch -> XCD.
// Block: 512 thr = 8 waves: rowgrp g = wid&1 (16 rows) x k-quarter h = wid>>1.
// K-loop: 64 iters x 128-vert tiles, double-buffered global_load_lds.
// w-gen: d2' = fma(px,vx', fma(py,vy', fma(pz,vz', vn'+pn2'))) (pre-scaled),
// w = exp2(-sqrt(max(d2',0))), all f32x4 packed; bf16 A-frag -> 4x mfma.
// ---------------------------------------------------------------------------
__global__ __launch_bounds__(512, 4) void fused_kernel(
    const float* __restrict__ locs_l, const float* __restrict__ locs_r,
    const uint16_t* __restrict__ fT2, const float* __restrict__ vS2,
    const float* __restrict__ w1, const float* __restrict__ b1,
    const float* __restrict__ w2, const float* __restrict__ b2,
    float* __restrict__ outp)
{
  __shared__ __align__(16) char  flds[2][16384];      // 2 x (2 subtiles x 8KB)
  __shared__ __align__(16) float vlds[2][2][4][64];   // [buf][sub][comp][v]
  __shared__ __align__(16) float xs[32][136];
  __shared__ float densp[32];

  const int bid  = blockIdx.x;
  const int bb   = bid & 7;
  const int tile = bid >> 3;          // 0..63
  const int tid  = threadIdx.x;
  const int wid  = tid >> 6, lane = tid & 63;
  const int g    = wid & 1, h = wid >> 1;      // h in [0,4): 32-vert quarter
  const int ln15 = lane & 15, lg = lane >> 4;
  const int xorv = (ln15 & 7) << 4;
  const f32x4 zero4 = {0.f, 0.f, 0.f, 0.f};

  const int sub  = h >> 1;            // which 8KB subtile
  const int hh   = h & 1;             // 32-vert half within subtile
  const int abfix = sub * 8192 + ln15 * 128 + ((((hh << 2) | lg) << 4) ^ xorv);

  for (int s = 0; s < 2; ++s) {
    const int p = s * 8 + bb;
    const float* locs = (s ? locs_r : locs_l) + (size_t)bb * (L_ * 3);
    const int arow = tile * 32 + g * 16 + ln15;
    const float px = locs[arow * 3 + 0];
    const float py = locs[arow * 3 + 1];
    const float pz = locs[arow * 3 + 2];
    const float pn2p = KEXP2 * (px * px + py * py + pz * pz);
    const f32x4 px4 = {px, px, px, px};
    const f32x4 py4 = {py, py, py, py};
    const f32x4 pz4 = {pz, pz, pz, pz};
    const f32x4 pn4 = {pn2p, pn2p, pn2p, pn2p};

    const char* ftp = (const char*)fT2 + (size_t)p * (128 * 8192);
    const char* vtp = (const char*)vS2 + (size_t)p * (128 * 1024);

    f32x4 acc0 = zero4, acc1 = zero4, acc2 = zero4, acc3 = zero4;
    f32x4 densa = zero4;

    // prologue: stage 128-vert tile 0
    gload_lds16(ftp + wid * 2048 + lane * 16,        &flds[0][wid * 2048]);
    gload_lds16(ftp + wid * 2048 + 1024 + lane * 16, &flds[0][wid * 2048 + 1024]);
    if (wid < 2) gload_lds16(vtp + wid * 1024 + lane * 16, &vlds[0][wid][0][0]);
    __syncthreads();

    for (int kt = 0; kt < 64; ++kt) {
      const int cur = kt & 1;
      if (kt < 63) {   // issue next-tile loads first; land by barrier drain
        const int nxt = cur ^ 1;
        const char* gf = ftp + (size_t)(kt + 1) * 16384 + wid * 2048;
        gload_lds16(gf + lane * 16,        &flds[nxt][wid * 2048]);
        gload_lds16(gf + 1024 + lane * 16, &flds[nxt][wid * 2048 + 1024]);
        if (wid < 2)
          gload_lds16(vtp + (size_t)(kt + 1) * 2048 + wid * 1024 + lane * 16,
                      &vlds[nxt][wid][0][0]);
      }
      const int kof = hh * 32 + lg * 8;
      const f32x4 vxa = *(const f32x4*)&vlds[cur][sub][0][kof];
      const f32x4 vxb = *(const f32x4*)&vlds[cur][sub][0][kof + 4];
      const f32x4 vya = *(const f32x4*)&vlds[cur][sub][1][kof];
      const f32x4 vyb = *(const f32x4*)&vlds[cur][sub][1][kof + 4];
      const f32x4 vza = *(const f32x4*)&vlds[cur][sub][2][kof];
      const f32x4 vzb = *(const f32x4*)&vlds[cur][sub][2][kof + 4];
      const f32x4 vna = *(const f32x4*)&vlds[cur][sub][3][kof];
      const f32x4 vnb = *(const f32x4*)&vlds[cur][sub][3][kof + 4];

      f32x4 d2a = PK_FMA4(vza, pz4, vna + pn4);
      d2a = PK_FMA4(vya, py4, d2a);
      d2a = PK_FMA4(vxa, px4, d2a);
      d2a = PK_MAX4(d2a, zero4);
      f32x4 d2b = PK_FMA4(vzb, pz4, vnb + pn4);
      d2b = PK_FMA4(vyb, py4, d2b);
      d2b = PK_FMA4(vxb, px4, d2b);
      d2b = PK_MAX4(d2b, zero4);

      f32x4 wa, wb;
      #pragma unroll
      for (int e = 0; e < 4; ++e) {
        wa[e] = EXP2(-__builtin_amdgcn_sqrtf(d2a[e]));
        wb[e] = EXP2(-__builtin_amdgcn_sqrtf(d2b[e]));
      }
      densa += wa;
      densa += wb;
      bf16x8 av;
      #pragma unroll
      for (int e = 0; e < 4; ++e) {
        av[e]     = (__bf16)wa[e];
        av[e + 4] = (__bf16)wb[e];
      }
      const s16x8 afrag = __builtin_bit_cast(s16x8, av);
      const char* fl = flds[cur];
      const s16x8 bf0 = *(const s16x8*)(fl + abfix);
      const s16x8 bf1 = *(const s16x8*)(fl + abfix + 2048);
      const s16x8 bf2 = *(const s16x8*)(fl + abfix + 4096);
      const s16x8 bf3 = *(const s16x8*)(fl + abfix + 6144);
      acc0 = __builtin_amdgcn_mfma_f32_16x16x32_bf16(afrag, bf0, acc0, 0, 0, 0);
      acc1 = __builtin_amdgcn_mfma_f32_16x16x32_bf16(afrag, bf1, acc1, 0, 0, 0);
      acc2 = __builtin_amdgcn_mfma_f32_16x16x32_bf16(afrag, bf2, acc2, 0, 0, 0);
      acc3 = __builtin_amdgcn_mfma_f32_16x16x32_bf16(afrag, bf3, acc3, 0, 0, 0);
      __syncthreads();
    }

    // lane -> quarter-dens of row (lane&15)
    float dens = (densa.x + densa.y) + (densa.z + densa.w);
    dens += __shfl_xor(dens, 16);
    dens += __shfl_xor(dens, 32);

    // merge 4 k-quarters through xs (phase h==0 writes, 1..3 add)
    #pragma unroll
    for (int ph = 0; ph < 4; ++ph) {
      if (h == ph) {
        if (ph == 0) {
          if (lane < 16) densp[g * 16 + lane] = dens;
          #pragma unroll
          for (int r = 0; r < 4; ++r) {
            const int row = g * 16 + lg * 4 + r;
            xs[row][s * 65 +      ln15] = acc0[r];
            xs[row][s * 65 + 16 + ln15] = acc1[r];
            xs[row][s * 65 + 32 + ln15] = acc2[r];
            xs[row][s * 65 + 48 + ln15] = acc3[r];
          }
        } else {
          if (lane < 16) densp[g * 16 + lane] += dens;
          #pragma unroll
          for (int r = 0; r < 4; ++r) {
            const int row = g * 16 + lg * 4 + r;
            xs[row][s * 65 +      ln15] += acc0[r];
            xs[row][s * 65 + 16 + ln15] += acc1[r];
            xs[row][s * 65 + 32 + ln15] += acc2[r];
            xs[row][s * 65 + 48 + ln15] += acc3[r];
          }
        }
      }
      __syncthreads();
    }
    // normalize by dens; col 64 holds raw dens
    for (int idx = tid; idx < 32 * 64; idx += 512) {
      const int row = idx >> 6, c = idx & 63;
      xs[row][s * 65 + c] *= (1.0f / densp[row]);
    }
    if (tid < 32) xs[tid][s * 65 + 64] = densp[tid];
    __syncthreads();
  }

  // -------------------- in-block MLP (fp32) --------------------
  const int r0 = wid * 4;                     // 4 rows per wave
  float hh0[4] = {0.f,0.f,0.f,0.f}, hh1[4] = {0.f,0.f,0.f,0.f};
  const float* wr0 = w1 + (size_t)lane * F_;
  const float* wr1 = w1 + (size_t)(lane + 64) * F_;

  #pragma unroll 4
  for (int i = 0; i < 128; i += 4) {
    const f32x2 a01 = *(const f32x2*)&wr0[i];
    const f32x2 a23 = *(const f32x2*)&wr0[i + 2];
    const f32x2 c01 = *(const f32x2*)&wr1[i];
    const f32x2 c23 = *(const f32x2*)&wr1[i + 2];
    #pragma unroll
    for (int r = 0; r < 4; ++r) {
      const f32x4 xv = *(const f32x4*)&xs[r0 + r][i];
      hh0[r] = fmaf(xv.x, a01.x, hh0[r]); hh0[r] = fmaf(xv.y, a01.y, hh0[r]);
      hh0[r] = fmaf(xv.z, a23.x, hh0[r]); hh0[r] = fmaf(xv.w, a23.y, hh0[r]);
      hh1[r] = fmaf(xv.x, c01.x, hh1[r]); hh1[r] = fmaf(xv.y, c01.y, hh1[r]);
      hh1[r] = fmaf(xv.z, c23.x, hh1[r]); hh1[r] = fmaf(xv.w, c23.y, hh1[r]);
    }
  }
  { // i-tail: 128,129
    const float a0 = wr0[128], a1 = wr0[129];
    const float c0 = wr1[128], c1 = wr1[129];
    #pragma unroll
    for (int r = 0; r < 4; ++r) {
      const float x0 = xs[r0 + r][128], x1 = xs[r0 + r][129];
      hh0[r] = fmaf(x0, a0, fmaf(x1, a1, hh0[r]));
      hh1[r] = fmaf(x0, c0, fmaf(x1, c1, hh1[r]));
    }
  }
  // j-tail: hidden cols 128,129 via per-row wave reduce
  const float* wr2 = w1 + 128 * F_;
  const float* wr3 = w1 + 129 * F_;
  float hp2[4], hp3[4];
  #pragma unroll
  for (int r = 0; r < 4; ++r) {
    const float xa = xs[r0 + r][lane];
    const float xb = xs[r0 + r][lane + 64];
    float p2 = wr2[lane] * xa + wr2[lane + 64] * xb;
    float p3 = wr3[lane] * xa + wr3[lane + 64] * xb;
    if (lane < 2) {
      const float xc = xs[r0 + r][128 + lane];
      p2 += wr2[128 + lane] * xc;
      p3 += wr3[128 + lane] * xc;
    }
    hp2[r] = wave_sum(p2);
    hp3[r] = wave_sum(p3);
  }
  const float b1a = b1[lane], b1b = b1[lane + 64];
  const float w2a = w2[lane], w2b = w2[lane + 64];
  const float b1c = b1[128], b1d = b1[129];
  const float w2c = w2[128], w2d = w2[129];
  const float b2v = b2[0];
  #pragma unroll
  for (int r = 0; r < 4; ++r) {
    float o = w2a * fmaxf(hh0[r] + b1a, 0.f) + w2b * fmaxf(hh1[r] + b1b, 0.f);
    o = wave_sum(o);
    if (lane == 0) {
      o += w2c * fmaxf(hp2[r] + b1c, 0.f) + w2d * fmaxf(hp3[r] + b1d, 0.f);
      outp[(size_t)bb * L_ + tile * 32 + r0 + r] = o + b2v;
    }
  }
}

// ---------------------------------------------------------------------------
extern "C" void kernel_launch(void* const* d_in, const int* in_sizes, int n_in,
                              void* d_out, int out_size, void* d_ws, size_t ws_size,
                              hipStream_t stream) {
  const float* locs_l  = (const float*)d_in[0];
  const float* locs_r  = (const float*)d_in[1];
  const float* verts_l = (const float*)d_in[2];
  const float* verts_r = (const float*)d_in[3];
  const float* feats_l = (const float*)d_in[4];
  const float* feats_r = (const float*)d_in[5];
  const float* w1 = (const float*)d_in[6];
  const float* b1 = (const float*)d_in[7];
  const float* w2 = (const float*)d_in[8];
  const float* b2 = (const float*)d_in[9];

  char* ws = (char*)d_ws;
  uint16_t* fT2 = (uint16_t*)ws;                 // 16 MiB swizzled feat tiles
  float*    vS2 = (float*)(ws + 16777216);       // 2 MiB pre-scaled vert tiles
  float*    out = (float*)d_out;

  pre_kernel<<<1536, 256, 0, stream>>>(verts_l, verts_r, feats_l, feats_r, fT2, vS2);
  fused_kernel<<<512, 512, 0, stream>>>(locs_l, locs_r, fT2, vS2,
                                        w1, b1, w2, b2, out);
}